// Round 5
// baseline (700.005 us; speedup 1.0000x reference)
//
#include <hip/hip_runtime.h>
#include <hip/hip_bf16.h>

using bf16 = __hip_bfloat16;
typedef __attribute__((ext_vector_type(8))) short bf16x8;
typedef __attribute__((ext_vector_type(4))) float f32x4;

__device__ __forceinline__ float toF(float x) { return x; }
__device__ __forceinline__ float toF(bf16 x) { return __bfloat162float(x); }

template <typename T> __device__ __forceinline__ T fromF(float x);
template <> __device__ __forceinline__ float fromF<float>(float x) { return x; }
template <> __device__ __forceinline__ bf16 fromF<bf16>(float x) { return __float2bfloat16(x); }

__device__ __forceinline__ unsigned short f2bu(float f) {
    bf16 h = __float2bfloat16(f);
    return *reinterpret_cast<unsigned short*>(&h);
}
__device__ __forceinline__ float bu2f(unsigned short u) {
    unsigned int x = ((unsigned int)u) << 16;
    return __uint_as_float(x);
}

// fast 2^x: raw v_exp_f32 (libm exp2f goes through slow OCML path)
__device__ __forceinline__ float fexp2(float x) {
#if __has_builtin(__builtin_amdgcn_exp2f)
    return __builtin_amdgcn_exp2f(x);
#else
    return __expf(x * 0.69314718f);
#endif
}

// async global->LDS, 16B per lane; LDS dest = wave-uniform base + lane*16
__device__ __forceinline__ void gload16(const unsigned short* g, unsigned short* l) {
    __builtin_amdgcn_global_load_lds(
        (const __attribute__((address_space(1))) unsigned int*)g,
        (__attribute__((address_space(3))) unsigned int*)l, 16, 0, 0);
}

// ---------------------------------------------------------------------------
// fp32 -> bf16 elementwise convert (vector 4/thread)
// ---------------------------------------------------------------------------
__global__ __launch_bounds__(256) void cvt_k(const float* __restrict__ X,
                                             unsigned short* __restrict__ Y, int n)
{
    int i = (blockIdx.x * 256 + threadIdx.x) * 4;
    if (i >= n) return;
    float4 v = *(const float4*)(X + i);
    ushort4 o;
    o.x = f2bu(v.x); o.y = f2bu(v.y); o.z = f2bu(v.z); o.w = f2bu(v.w);
    *(ushort4*)(Y + i) = o;
}

// ---------------------------------------------------------------------------
// Weight transpose: W fp32 (K,N) [or head-stacked (H,K,64), n=(h<<6)+dh]
//   -> Wt bf16 (N,K).  32x32 LDS tile, 256 threads.
//   blockIdx.z selects one of up to 3 source weights (batched QKV / KV).
// ---------------------------------------------------------------------------
struct WPtrs { const float* w[3]; };

template <bool HEADED>
__global__ __launch_bounds__(256) void wtrans_k(
    WPtrs wp, unsigned short* __restrict__ Wt, int K, int N)
{
    __shared__ float t[32][33];
    const float* __restrict__ W = wp.w[blockIdx.z];
    unsigned short* __restrict__ out = Wt + (size_t)blockIdx.z * K * N;
    const int k0 = blockIdx.x * 32, n0 = blockIdx.y * 32;
    const int tx = threadIdx.x & 31, ty = threadIdx.x >> 5;
#pragma unroll
    for (int i = 0; i < 4; i++) {
        int k = k0 + ty + 8 * i, n = n0 + tx;
        float v;
        if constexpr (HEADED) v = W[((size_t)(n >> 6) * K + k) * 64 + (n & 63)];
        else                  v = W[(size_t)k * N + n];
        t[ty + 8 * i][tx] = v;
    }
    __syncthreads();
#pragma unroll
    for (int i = 0; i < 4; i++)
        out[(size_t)(n0 + ty + 8 * i) * K + k0 + tx] = f2bu(t[tx][ty + 8 * i]);
}

// ---------------------------------------------------------------------------
// MFMA GEMM, global_load_lds staging + XOR-swizzled LDS (verified round 2).
//   C(M,N) = A(M,K)bf16 @ Bt(N,K)bf16^T + bias [+res] [ReLU]
// ---------------------------------------------------------------------------
template <typename TO, typename TR, bool RELU, bool HASRES, int BN>
__global__ __launch_bounds__(256) void gemm_mfma(
    const unsigned short* __restrict__ A, const unsigned short* __restrict__ Bt,
    const float* __restrict__ bias, const TR* __restrict__ res,
    TO* __restrict__ C, int M, int N, int K)
{
    constexpr int MI = (BN == 128) ? 4 : 2;
    __shared__ __align__(16) unsigned short As[128 * 64];
    __shared__ __align__(16) unsigned short Bs[BN * 64];

    const int tid = threadIdx.x;
    const int lane = tid & 63, wv = tid >> 6;
    const int quad = lane >> 4, col = lane & 15;
    const int m0 = blockIdx.y * 128, n0 = blockIdx.x * BN;
    const int wm = (BN == 128) ? (wv >> 1) * 64 : wv * 32;
    const int wn = (BN == 128) ? (wv & 1) * 64 : 0;

    f32x4 acc[MI][4];
#pragma unroll
    for (int i = 0; i < MI; i++)
#pragma unroll
        for (int j = 0; j < 4; j++) acc[i][j] = (f32x4){0.f, 0.f, 0.f, 0.f};

    const int rowl = (wv << 3) + (lane >> 3);
    const int xq = (lane & 7) ^ (lane >> 3);
    const unsigned short* Ag = A + (size_t)(m0 + rowl) * K + xq * 8;
    const unsigned short* Bg = Bt + (size_t)(n0 + rowl) * K + xq * 8;
    unsigned short* AsW = As + wv * 512;
    unsigned short* BsW = Bs + wv * 512;

    const int xr = col & 7;

    for (int k0 = 0; k0 < K; k0 += 64) {
        __syncthreads();
#pragma unroll
        for (int r = 0; r < 4; r++)
            gload16(Ag + (size_t)(r * 32) * K + k0, AsW + r * 2048);
#pragma unroll
        for (int r = 0; r < BN / 32; r++)
            gload16(Bg + (size_t)(r * 32) * K + k0, BsW + r * 2048);
        __syncthreads();

#pragma unroll
        for (int kk = 0; kk < 2; kk++) {
            const int cq = ((kk << 2) + quad) ^ xr;
            bf16x8 af[MI], bfr[4];
#pragma unroll
            for (int mi = 0; mi < MI; mi++)
                af[mi] = *(const bf16x8*)(As + (wm + mi * 16 + col) * 64 + cq * 8);
#pragma unroll
            for (int ni = 0; ni < 4; ni++)
                bfr[ni] = *(const bf16x8*)(Bs + (wn + ni * 16 + col) * 64 + cq * 8);
#pragma unroll
            for (int mi = 0; mi < MI; mi++)
#pragma unroll
                for (int ni = 0; ni < 4; ni++)
                    acc[mi][ni] = __builtin_amdgcn_mfma_f32_16x16x32_bf16(
                        af[mi], bfr[ni], acc[mi][ni], 0, 0, 0);
        }
    }

    float bv[4];
#pragma unroll
    for (int ni = 0; ni < 4; ni++) bv[ni] = bias[n0 + wn + ni * 16 + col];
#pragma unroll
    for (int mi = 0; mi < MI; mi++) {
#pragma unroll
        for (int r = 0; r < 4; r++) {
            int m = m0 + wm + mi * 16 + quad * 4 + r;
#pragma unroll
            for (int ni = 0; ni < 4; ni++) {
                int n = n0 + wn + ni * 16 + col;
                float v = acc[mi][ni][r] + bv[ni];
                if constexpr (HASRES) v += toF(res[(size_t)m * N + n]);
                if constexpr (RELU) v = v > 0.f ? v : 0.f;
                C[(size_t)m * N + n] = fromF<TO>(v);
            }
        }
    }
}

// ---------------------------------------------------------------------------
// Segmented MFMA GEMM (QKV / KV fused), same gload_lds+swizzle K-loop.
// ---------------------------------------------------------------------------
struct SegArgs {
    const float* bias[3];
    unsigned short* out[3];
};

__global__ __launch_bounds__(256) void gemm_seg(
    const unsigned short* __restrict__ A, const unsigned short* __restrict__ Bt,
    SegArgs sp, int M, int K, int transSeg)
{
    __shared__ __align__(16) unsigned short As[128 * 64];
    __shared__ __align__(16) unsigned short Bs[128 * 64];

    const int tid = threadIdx.x;
    const int lane = tid & 63, wv = tid >> 6;
    const int quad = lane >> 4, col = lane & 15;
    const int m0 = blockIdx.y * 128, n0 = blockIdx.x * 128;
    const int wm = (wv >> 1) * 64, wn = (wv & 1) * 64;

    f32x4 acc[4][4];
#pragma unroll
    for (int i = 0; i < 4; i++)
#pragma unroll
        for (int j = 0; j < 4; j++) acc[i][j] = (f32x4){0.f, 0.f, 0.f, 0.f};

    const int rowl = (wv << 3) + (lane >> 3);
    const int xq = (lane & 7) ^ (lane >> 3);
    const unsigned short* Ag = A + (size_t)(m0 + rowl) * K + xq * 8;
    const unsigned short* Bg = Bt + (size_t)(n0 + rowl) * K + xq * 8;
    unsigned short* AsW = As + wv * 512;
    unsigned short* BsW = Bs + wv * 512;
    const int xr = col & 7;

    for (int k0 = 0; k0 < K; k0 += 64) {
        __syncthreads();
#pragma unroll
        for (int r = 0; r < 4; r++)
            gload16(Ag + (size_t)(r * 32) * K + k0, AsW + r * 2048);
#pragma unroll
        for (int r = 0; r < 4; r++)
            gload16(Bg + (size_t)(r * 32) * K + k0, BsW + r * 2048);
        __syncthreads();

#pragma unroll
        for (int kk = 0; kk < 2; kk++) {
            const int cq = ((kk << 2) + quad) ^ xr;
            bf16x8 af[4], bfr[4];
#pragma unroll
            for (int mi = 0; mi < 4; mi++)
                af[mi] = *(const bf16x8*)(As + (wm + mi * 16 + col) * 64 + cq * 8);
#pragma unroll
            for (int ni = 0; ni < 4; ni++)
                bfr[ni] = *(const bf16x8*)(Bs + (wn + ni * 16 + col) * 64 + cq * 8);
#pragma unroll
            for (int mi = 0; mi < 4; mi++)
#pragma unroll
                for (int ni = 0; ni < 4; ni++)
                    acc[mi][ni] = __builtin_amdgcn_mfma_f32_16x16x32_bf16(
                        af[mi], bfr[ni], acc[mi][ni], 0, 0, 0);
        }
    }

    const int seg = n0 >> 10;
    const float* bias = sp.bias[seg];
    unsigned short* out = sp.out[seg];
    const int nb = (n0 & 1023) + wn;
    const bool trans = (seg == transSeg);

    float bv[4];
#pragma unroll
    for (int ni = 0; ni < 4; ni++) bv[ni] = bias[nb + ni * 16 + col];
#pragma unroll
    for (int mi = 0; mi < 4; mi++) {
#pragma unroll
        for (int r = 0; r < 4; r++) {
            int m = m0 + wm + mi * 16 + quad * 4 + r;
#pragma unroll
            for (int ni = 0; ni < 4; ni++) {
                int nl = nb + ni * 16 + col;
                float v = acc[mi][ni][r] + bv[ni];
                if (trans)
                    out[((size_t)(m >> 10) * 1024 + nl) * 1024 + (m & 1023)] = f2bu(v);
                else
                    out[(size_t)m * 1024 + nl] = f2bu(v);
            }
        }
    }
}

// ---------------------------------------------------------------------------
// Flash attention, MFMA 16x16x32 bf16 — barrier-free version.
//  K/V tiles are L1/L2-resident at these sizes (8KB tile, 256KB per head):
//  MFMA fragments are read DIRECTLY from global (no LDS staging, no
//  __syncthreads anywhere). P transpose uses per-wave LDS (same-wave
//  ds_write->ds_read, lgkmcnt-ordered). Fast v_exp_f32 via builtin.
//  LDS 9KB -> occupancy cap 8 blocks/CU (was 2.5).
// ---------------------------------------------------------------------------
template <bool CAUSAL>
__global__ __launch_bounds__(256) void fattn_k(
    const unsigned short* __restrict__ Q, const unsigned short* __restrict__ K,
    const unsigned short* __restrict__ Vt, unsigned short* __restrict__ O, int S)
{
    const int qt = CAUSAL ? ((int)gridDim.x - 1 - (int)blockIdx.x) : blockIdx.x;
    const int h = blockIdx.y, b = blockIdx.z;
    const int H64 = 1024;
    const int tid = threadIdx.x;
    const int w = tid >> 6, lane = tid & 63;
    const int quad = lane >> 4, col = lane & 15;

    __shared__ __align__(16) unsigned short Ps[4 * 16 * 72];

    const int qBase = qt * 64 + w * 16;
    const size_t qrow = ((size_t)b * S + qBase + col) * H64 + h * 64;

    // Q fragments pre-scaled by 0.125*log2(e): scores come out in log2 units.
    const float qscale = 0.125f * 1.44269504f;
    bf16x8 qf0, qf1;
    {
        bf16x8 r0 = *(const bf16x8*)(Q + qrow + quad * 8);
        bf16x8 r1 = *(const bf16x8*)(Q + qrow + quad * 8 + 32);
#pragma unroll
        for (int j = 0; j < 8; j++) {
            qf0[j] = (short)f2bu(bu2f((unsigned short)r0[j]) * qscale);
            qf1[j] = (short)f2bu(bu2f((unsigned short)r1[j]) * qscale);
        }
    }

    f32x4 o[4];
#pragma unroll
    for (int g = 0; g < 4; g++) o[g] = (f32x4){0.f, 0.f, 0.f, 0.f};
    float m_run[4], l_run[4];
#pragma unroll
    for (int r = 0; r < 4; r++) { m_run[r] = -1e30f; l_run[r] = 0.f; }

    const size_t kgbase = (size_t)b * S * H64 + h * 64;
    const size_t vgbase = ((size_t)b * 1024 + h * 64) * (size_t)S;

    const int nkt = CAUSAL ? (qt + 1) : (S >> 6);
    unsigned short* Pw = Ps + w * (16 * 72);

    for (int kt = 0; kt < nkt; kt++) {
        // QK^T: K fragments straight from global (L1-resident tile)
        f32x4 s[4];
#pragma unroll
        for (int kg = 0; kg < 4; kg++) {
            const unsigned short* kr =
                K + kgbase + (size_t)(kt * 64 + kg * 16 + col) * H64 + quad * 8;
            bf16x8 k0 = *(const bf16x8*)(kr);
            bf16x8 k1 = *(const bf16x8*)(kr + 32);
            f32x4 a = (f32x4){0.f, 0.f, 0.f, 0.f};
            a = __builtin_amdgcn_mfma_f32_16x16x32_bf16(qf0, k0, a, 0, 0, 0);
            a = __builtin_amdgcn_mfma_f32_16x16x32_bf16(qf1, k1, a, 0, 0, 0);
            s[kg] = a;
        }

        // causal mask: only the diagonal tile needs it (wave-uniform branch)
        if (CAUSAL && kt == qt) {
#pragma unroll
            for (int kg = 0; kg < 4; kg++)
#pragma unroll
                for (int r = 0; r < 4; r++) {
                    int key = kg * 16 + col;
                    int q = w * 16 + quad * 4 + r;
                    if (key > q) s[kg][r] = -1e30f;
                }
        }

        float mx[4];
#pragma unroll
        for (int r = 0; r < 4; r++) {
            float m2 = fmaxf(fmaxf(s[0][r], s[1][r]), fmaxf(s[2][r], s[3][r]));
#pragma unroll
            for (int off = 1; off < 16; off <<= 1)
                m2 = fmaxf(m2, __shfl_xor(m2, off));
            mx[r] = m2;
        }

        // T13 defer-max: skip rescale when max growth <= 8 (P bounded by 2^8)
        bool defer = (mx[0] <= m_run[0] + 8.f) & (mx[1] <= m_run[1] + 8.f)
                   & (mx[2] <= m_run[2] + 8.f) & (mx[3] <= m_run[3] + 8.f);
        if (!__all(defer)) {
#pragma unroll
            for (int r = 0; r < 4; r++) {
                float mnew = fmaxf(m_run[r], mx[r]);
                float alpha = fexp2(m_run[r] - mnew);
                l_run[r] *= alpha;
#pragma unroll
                for (int g = 0; g < 4; g++) o[g][r] *= alpha;
                m_run[r] = mnew;
            }
        }

#pragma unroll
        for (int r = 0; r < 4; r++) {
            float ps = 0.f;
#pragma unroll
            for (int kg = 0; kg < 4; kg++) {
                float e = fexp2(s[kg][r] - m_run[r]);
                s[kg][r] = e;
                ps += e;
            }
#pragma unroll
            for (int off = 1; off < 16; off <<= 1)
                ps += __shfl_xor(ps, off);
            l_run[r] += ps;
        }

        // P transpose via per-wave LDS slab (no barrier: same-wave order)
#pragma unroll
        for (int kg = 0; kg < 4; kg++)
#pragma unroll
            for (int r = 0; r < 4; r++)
                Pw[(quad * 4 + r) * 72 + kg * 16 + col] = f2bu(s[kg][r]);

        bf16x8 p0 = *(const bf16x8*)(Pw + col * 72 + quad * 8);
        bf16x8 p1 = *(const bf16x8*)(Pw + col * 72 + quad * 8 + 32);

        // PV: V^T fragments straight from global (L1-resident tile)
#pragma unroll
        for (int g = 0; g < 4; g++) {
            const unsigned short* vr =
                Vt + vgbase + (size_t)(g * 16 + col) * S + kt * 64 + quad * 8;
            bf16x8 v0 = *(const bf16x8*)(vr);
            bf16x8 v1 = *(const bf16x8*)(vr + 32);
            o[g] = __builtin_amdgcn_mfma_f32_16x16x32_bf16(p0, v0, o[g], 0, 0, 0);
            o[g] = __builtin_amdgcn_mfma_f32_16x16x32_bf16(p1, v1, o[g], 0, 0, 0);
        }
    }

    const size_t orow = ((size_t)b * S + qBase) * H64 + h * 64;
#pragma unroll
    for (int r = 0; r < 4; r++) {
        float inv = 1.f / l_run[r];
        int q = quad * 4 + r;
#pragma unroll
        for (int g = 0; g < 4; g++)
            O[orow + (size_t)q * H64 + g * 16 + col] = f2bu(o[g][r] * inv);
    }
}

// ---------------------------------------------------------------------------
// LayerNorm (ddof=1, eps=1e-12)
// ---------------------------------------------------------------------------
template <typename TO>
__global__ __launch_bounds__(256) void ln_k(
    const float* __restrict__ X, const float* __restrict__ g,
    const float* __restrict__ bb, TO* __restrict__ O, int D)
{
    const int row = blockIdx.x;
    const int tid = threadIdx.x;
    __shared__ float xs[1024];
    __shared__ float red[256];
    const float* x = X + (size_t)row * D;

    float s = 0.f;
    for (int i = tid; i < D; i += 256) { float v = x[i]; xs[i] = v; s += v; }
    red[tid] = s;
    __syncthreads();
    for (int t = 128; t > 0; t >>= 1) {
        if (tid < t) red[tid] += red[tid + t];
        __syncthreads();
    }
    const float mean = red[0] / (float)D;
    __syncthreads();

    float s2 = 0.f;
    for (int i = tid; i < D; i += 256) { float d = xs[i] - mean; s2 += d * d; }
    red[tid] = s2;
    __syncthreads();
    for (int t = 128; t > 0; t >>= 1) {
        if (tid < t) red[tid] += red[tid + t];
        __syncthreads();
    }
    const float rstd = rsqrtf(red[0] / (float)(D - 1) + 1e-12f);

    TO* o = O + (size_t)row * D;
    for (int i = tid; i < D; i += 256)
        o[i] = fromF<TO>(g[i] * (xs[i] - mean) * rstd + bb[i]);
}

// ---------------------------------------------------------------------------
extern "C" void kernel_launch(void* const* d_in, const int* in_sizes, int n_in,
                              void* d_out, int out_size, void* d_ws, size_t ws_size,
                              hipStream_t stream)
{
    const int Bb = 4, S = 1024, D = 1024, F = 4096;
    const int M = Bb * S;
    const int H = 16;

    const float* dec = (const float*)d_in[0];
    const float* enc = (const float*)d_in[1];

    int base = 2;
    if (n_in >= 29 && in_sizes[2] == Bb * S * S) base = 3;

    const float* sa_wq = (const float*)d_in[base + 0];
    const float* sa_wk = (const float*)d_in[base + 1];
    const float* sa_wv = (const float*)d_in[base + 2];
    const float* sa_bq = (const float*)d_in[base + 3];
    const float* sa_bk = (const float*)d_in[base + 4];
    const float* sa_bv = (const float*)d_in[base + 5];
    const float* sa_wo = (const float*)d_in[base + 6];
    const float* sa_bo = (const float*)d_in[base + 7];
    const float* ca_wq = (const float*)d_in[base + 8];
    const float* ca_wk = (const float*)d_in[base + 9];
    const float* ca_wv = (const float*)d_in[base + 10];
    const float* ca_bq = (const float*)d_in[base + 11];
    const float* ca_bk = (const float*)d_in[base + 12];
    const float* ca_bv = (const float*)d_in[base + 13];
    const float* ca_wo = (const float*)d_in[base + 14];
    const float* ca_bo = (const float*)d_in[base + 15];
    const float* ff_w1 = (const float*)d_in[base + 16];
    const float* ff_b1 = (const float*)d_in[base + 17];
    const float* ff_w2 = (const float*)d_in[base + 18];
    const float* ff_b2 = (const float*)d_in[base + 19];
    const float* ln1_g = (const float*)d_in[base + 20];
    const float* ln1_b = (const float*)d_in[base + 21];
    const float* ln2_g = (const float*)d_in[base + 22];
    const float* ln2_b = (const float*)d_in[base + 23];
    const float* ln3_g = (const float*)d_in[base + 24];
    const float* ln3_b = (const float*)d_in[base + 25];

    // ws (64 MiB): SUM fp32 E | O1 bf16 E | O2 bf16 E | Q | K | Vt | AO (bf16 E each)
    //   HID bf16 4E overlays [Q..AO] (FFN phase); decB overlays AO (pre-attn phase).
    // d_out (16 MiB fp32) doubles as scratch until the final LN:
    //   Wt bf16 [0,8MiB) transposed weight (QKV fused: 6MiB); encB [8,16MiB).
    const size_t E = (size_t)M * D;
    float* SUM = (float*)d_ws;
    bf16* O1 = (bf16*)(SUM + E);
    bf16* O2 = O1 + E;
    bf16* Q  = O2 + E;
    bf16* Kb = Q + E;
    bf16* Vt = Kb + E;
    bf16* AO = Vt + E;
    bf16* HID = Q;
    unsigned short* decB = (unsigned short*)AO;           // dead once fattn writes AO
    unsigned short* Wt   = (unsigned short*)d_out;        // 8 MiB slot
    unsigned short* encB = (unsigned short*)d_out + 4 * 1024 * 1024;

    dim3 blk(256);
    dim3 gQKV(3 * D / 128, M / 128); // fused QKV: 24 x 32 = 768 blocks
    dim3 gKV(2 * D / 128, M / 128);  // fused KV:  16 x 32 = 512 blocks
    dim3 gN(D / 64, M / 128);        // narrow N=1024 gemms: 16 x 32 = 512 blocks
    dim3 gF(F / 128, M / 128);       // N=4096: 32 x 32
    dim3 gA(S / 64, H, Bb);
    dim3 gT3(D / 32, D / 32, 3);     // batched QKV transpose
    dim3 gT2z(D / 32, D / 32, 2);    // batched KV transpose
    dim3 gT(D / 32, D / 32, 1);      // single transpose K=N=1024
    dim3 gT1(D / 32, F / 32, 1);     // ff_w1: K=1024, N=4096
    dim3 gT2(F / 32, D / 32, 1);     // ff_w2: K=4096, N=1024

    // input converts
    cvt_k<<<M * D / 1024, blk, 0, stream>>>(dec, decB, M * D);
    cvt_k<<<M * D / 1024, blk, 0, stream>>>(enc, encB, M * D);

    // --- self-attention: fused QKV projection ---
    {
        WPtrs wp; wp.w[0] = sa_wq; wp.w[1] = sa_wk; wp.w[2] = sa_wv;
        wtrans_k<true><<<gT3, blk, 0, stream>>>(wp, Wt, D, D);
    }
    {
        SegArgs sp;
        sp.bias[0] = sa_bq; sp.bias[1] = sa_bk; sp.bias[2] = sa_bv;
        sp.out[0] = (unsigned short*)Q; sp.out[1] = (unsigned short*)Kb;
        sp.out[2] = (unsigned short*)Vt;
        gemm_seg<<<gQKV, blk, 0, stream>>>(decB, Wt, sp, M, D, 2);
    }
    fattn_k<true><<<gA, blk, 0, stream>>>((const unsigned short*)Q, (const unsigned short*)Kb,
                                          (const unsigned short*)Vt, (unsigned short*)AO, S);
    {
        WPtrs wp; wp.w[0] = sa_wo; wp.w[1] = nullptr; wp.w[2] = nullptr;
        wtrans_k<false><<<gT, blk, 0, stream>>>(wp, Wt, D, D);
    }
    gemm_mfma<float, float, false, true, 64><<<gN, blk, 0, stream>>>(
        (const unsigned short*)AO, Wt, sa_bo, dec, SUM, M, D, D);
    ln_k<bf16><<<M, blk, 0, stream>>>(SUM, ln1_g, ln1_b, O1, D);

    // --- cross-attention: Q separate (A=O1), fused KV (A=encB) ---
    {
        WPtrs wp; wp.w[0] = ca_wq; wp.w[1] = nullptr; wp.w[2] = nullptr;
        wtrans_k<true><<<gT, blk, 0, stream>>>(wp, Wt, D, D);
    }
    gemm_mfma<bf16, float, false, false, 64><<<gN, blk, 0, stream>>>(
        (const unsigned short*)O1, Wt, ca_bq, (const float*)nullptr, Q, M, D, D);
    {
        WPtrs wp; wp.w[0] = ca_wk; wp.w[1] = ca_wv; wp.w[2] = nullptr;
        wtrans_k<true><<<gT2z, blk, 0, stream>>>(wp, Wt, D, D);
    }
    {
        SegArgs sp;
        sp.bias[0] = ca_bk; sp.bias[1] = ca_bv; sp.bias[2] = nullptr;
        sp.out[0] = (unsigned short*)Kb; sp.out[1] = (unsigned short*)Vt;
        sp.out[2] = nullptr;
        gemm_seg<<<gKV, blk, 0, stream>>>(encB, Wt, sp, M, D, 1);
    }
    fattn_k<false><<<gA, blk, 0, stream>>>((const unsigned short*)Q, (const unsigned short*)Kb,
                                           (const unsigned short*)Vt, (unsigned short*)AO, S);
    {
        WPtrs wp; wp.w[0] = ca_wo; wp.w[1] = nullptr; wp.w[2] = nullptr;
        wtrans_k<false><<<gT, blk, 0, stream>>>(wp, Wt, D, D);
    }
    gemm_mfma<float, bf16, false, true, 64><<<gN, blk, 0, stream>>>(
        (const unsigned short*)AO, Wt, ca_bo, O1, SUM, M, D, D);
    ln_k<bf16><<<M, blk, 0, stream>>>(SUM, ln2_g, ln2_b, O2, D);

    // --- FFN ---
    {
        WPtrs wp; wp.w[0] = ff_w1; wp.w[1] = nullptr; wp.w[2] = nullptr;
        wtrans_k<false><<<gT1, blk, 0, stream>>>(wp, Wt, D, F);
    }
    gemm_mfma<bf16, float, true, false, 128><<<gF, blk, 0, stream>>>(
        (const unsigned short*)O2, Wt, ff_b1, (const float*)nullptr, HID, M, F, D);
    {
        WPtrs wp; wp.w[0] = ff_w2; wp.w[1] = nullptr; wp.w[2] = nullptr;
        wtrans_k<false><<<gT2, blk, 0, stream>>>(wp, Wt, F, D);
    }
    gemm_mfma<float, bf16, false, true, 64><<<gN, blk, 0, stream>>>(
        (const unsigned short*)HID, Wt, ff_b2, O2, SUM, M, D, F);
    ln_k<float><<<M, blk, 0, stream>>>(SUM, ln3_g, ln3_b, (float*)d_out, D);
}

// Round 7
// 579.540 us; speedup vs baseline: 1.2079x; 1.2079x over previous
//
#include <hip/hip_runtime.h>
#include <hip/hip_bf16.h>

using bf16 = __hip_bfloat16;
typedef __attribute__((ext_vector_type(8))) short bf16x8;
typedef __attribute__((ext_vector_type(4))) float f32x4;

__device__ __forceinline__ float toF(float x) { return x; }
__device__ __forceinline__ float toF(bf16 x) { return __bfloat162float(x); }

template <typename T> __device__ __forceinline__ T fromF(float x);
template <> __device__ __forceinline__ float fromF<float>(float x) { return x; }
template <> __device__ __forceinline__ bf16 fromF<bf16>(float x) { return __float2bfloat16(x); }

__device__ __forceinline__ unsigned short f2bu(float f) {
    bf16 h = __float2bfloat16(f);
    return *reinterpret_cast<unsigned short*>(&h);
}
__device__ __forceinline__ float bu2f(unsigned short u) {
    unsigned int x = ((unsigned int)u) << 16;
    return __uint_as_float(x);
}

// fast 2^x: raw v_exp_f32 (libm exp2f goes through slow OCML path)
__device__ __forceinline__ float fexp2(float x) {
#if __has_builtin(__builtin_amdgcn_exp2f)
    return __builtin_amdgcn_exp2f(x);
#else
    return __expf(x * 0.69314718f);
#endif
}

// async global->LDS, 16B per lane; LDS dest = wave-uniform base + lane*16
__device__ __forceinline__ void gload16(const unsigned short* g, unsigned short* l) {
    __builtin_amdgcn_global_load_lds(
        (const __attribute__((address_space(1))) unsigned int*)g,
        (__attribute__((address_space(3))) unsigned int*)l, 16, 0, 0);
}

// ---------------------------------------------------------------------------
// fp32 -> bf16 elementwise convert (vector 4/thread)
// ---------------------------------------------------------------------------
__global__ __launch_bounds__(256) void cvt_k(const float* __restrict__ X,
                                             unsigned short* __restrict__ Y, int n)
{
    int i = (blockIdx.x * 256 + threadIdx.x) * 4;
    if (i >= n) return;
    float4 v = *(const float4*)(X + i);
    ushort4 o;
    o.x = f2bu(v.x); o.y = f2bu(v.y); o.z = f2bu(v.z); o.w = f2bu(v.w);
    *(ushort4*)(Y + i) = o;
}

// ---------------------------------------------------------------------------
// Weight transpose: W fp32 (K,N) [or head-stacked (H,K,64), n=(h<<6)+dh]
//   -> Wt bf16 (N,K).  32x32 LDS tile, 256 threads.
//   blockIdx.z selects one of up to 3 source weights (batched QKV / KV).
// ---------------------------------------------------------------------------
struct WPtrs { const float* w[3]; };

template <bool HEADED>
__global__ __launch_bounds__(256) void wtrans_k(
    WPtrs wp, unsigned short* __restrict__ Wt, int K, int N)
{
    __shared__ float t[32][33];
    const float* __restrict__ W = wp.w[blockIdx.z];
    unsigned short* __restrict__ out = Wt + (size_t)blockIdx.z * K * N;
    const int k0 = blockIdx.x * 32, n0 = blockIdx.y * 32;
    const int tx = threadIdx.x & 31, ty = threadIdx.x >> 5;
#pragma unroll
    for (int i = 0; i < 4; i++) {
        int k = k0 + ty + 8 * i, n = n0 + tx;
        float v;
        if constexpr (HEADED) v = W[((size_t)(n >> 6) * K + k) * 64 + (n & 63)];
        else                  v = W[(size_t)k * N + n];
        t[ty + 8 * i][tx] = v;
    }
    __syncthreads();
#pragma unroll
    for (int i = 0; i < 4; i++)
        out[(size_t)(n0 + ty + 8 * i) * K + k0 + tx] = f2bu(t[tx][ty + 8 * i]);
}

// ---------------------------------------------------------------------------
// MFMA GEMM, global_load_lds staging + XOR-swizzled LDS (verified round 2).
//   C(M,N) = A(M,K)bf16 @ Bt(N,K)bf16^T + bias [+res] [ReLU]
// ---------------------------------------------------------------------------
template <typename TO, typename TR, bool RELU, bool HASRES, int BN>
__global__ __launch_bounds__(256) void gemm_mfma(
    const unsigned short* __restrict__ A, const unsigned short* __restrict__ Bt,
    const float* __restrict__ bias, const TR* __restrict__ res,
    TO* __restrict__ C, int M, int N, int K)
{
    constexpr int MI = (BN == 128) ? 4 : 2;
    __shared__ __align__(16) unsigned short As[128 * 64];
    __shared__ __align__(16) unsigned short Bs[BN * 64];

    const int tid = threadIdx.x;
    const int lane = tid & 63, wv = tid >> 6;
    const int quad = lane >> 4, col = lane & 15;
    const int m0 = blockIdx.y * 128, n0 = blockIdx.x * BN;
    const int wm = (BN == 128) ? (wv >> 1) * 64 : wv * 32;
    const int wn = (BN == 128) ? (wv & 1) * 64 : 0;

    f32x4 acc[MI][4];
#pragma unroll
    for (int i = 0; i < MI; i++)
#pragma unroll
        for (int j = 0; j < 4; j++) acc[i][j] = (f32x4){0.f, 0.f, 0.f, 0.f};

    const int rowl = (wv << 3) + (lane >> 3);
    const int xq = (lane & 7) ^ (lane >> 3);
    const unsigned short* Ag = A + (size_t)(m0 + rowl) * K + xq * 8;
    const unsigned short* Bg = Bt + (size_t)(n0 + rowl) * K + xq * 8;
    unsigned short* AsW = As + wv * 512;
    unsigned short* BsW = Bs + wv * 512;

    const int xr = col & 7;

    for (int k0 = 0; k0 < K; k0 += 64) {
        __syncthreads();
#pragma unroll
        for (int r = 0; r < 4; r++)
            gload16(Ag + (size_t)(r * 32) * K + k0, AsW + r * 2048);
#pragma unroll
        for (int r = 0; r < BN / 32; r++)
            gload16(Bg + (size_t)(r * 32) * K + k0, BsW + r * 2048);
        __syncthreads();

#pragma unroll
        for (int kk = 0; kk < 2; kk++) {
            const int cq = ((kk << 2) + quad) ^ xr;
            bf16x8 af[MI], bfr[4];
#pragma unroll
            for (int mi = 0; mi < MI; mi++)
                af[mi] = *(const bf16x8*)(As + (wm + mi * 16 + col) * 64 + cq * 8);
#pragma unroll
            for (int ni = 0; ni < 4; ni++)
                bfr[ni] = *(const bf16x8*)(Bs + (wn + ni * 16 + col) * 64 + cq * 8);
#pragma unroll
            for (int mi = 0; mi < MI; mi++)
#pragma unroll
                for (int ni = 0; ni < 4; ni++)
                    acc[mi][ni] = __builtin_amdgcn_mfma_f32_16x16x32_bf16(
                        af[mi], bfr[ni], acc[mi][ni], 0, 0, 0);
        }
    }

    float bv[4];
#pragma unroll
    for (int ni = 0; ni < 4; ni++) bv[ni] = bias[n0 + wn + ni * 16 + col];
#pragma unroll
    for (int mi = 0; mi < MI; mi++) {
#pragma unroll
        for (int r = 0; r < 4; r++) {
            int m = m0 + wm + mi * 16 + quad * 4 + r;
#pragma unroll
            for (int ni = 0; ni < 4; ni++) {
                int n = n0 + wn + ni * 16 + col;
                float v = acc[mi][ni][r] + bv[ni];
                if constexpr (HASRES) v += toF(res[(size_t)m * N + n]);
                if constexpr (RELU) v = v > 0.f ? v : 0.f;
                C[(size_t)m * N + n] = fromF<TO>(v);
            }
        }
    }
}

// ---------------------------------------------------------------------------
// Segmented MFMA GEMM (QKV / KV fused), same gload_lds+swizzle K-loop.
// ---------------------------------------------------------------------------
struct SegArgs {
    const float* bias[3];
    unsigned short* out[3];
};

__global__ __launch_bounds__(256) void gemm_seg(
    const unsigned short* __restrict__ A, const unsigned short* __restrict__ Bt,
    SegArgs sp, int M, int K, int transSeg)
{
    __shared__ __align__(16) unsigned short As[128 * 64];
    __shared__ __align__(16) unsigned short Bs[128 * 64];

    const int tid = threadIdx.x;
    const int lane = tid & 63, wv = tid >> 6;
    const int quad = lane >> 4, col = lane & 15;
    const int m0 = blockIdx.y * 128, n0 = blockIdx.x * 128;
    const int wm = (wv >> 1) * 64, wn = (wv & 1) * 64;

    f32x4 acc[4][4];
#pragma unroll
    for (int i = 0; i < 4; i++)
#pragma unroll
        for (int j = 0; j < 4; j++) acc[i][j] = (f32x4){0.f, 0.f, 0.f, 0.f};

    const int rowl = (wv << 3) + (lane >> 3);
    const int xq = (lane & 7) ^ (lane >> 3);
    const unsigned short* Ag = A + (size_t)(m0 + rowl) * K + xq * 8;
    const unsigned short* Bg = Bt + (size_t)(n0 + rowl) * K + xq * 8;
    unsigned short* AsW = As + wv * 512;
    unsigned short* BsW = Bs + wv * 512;
    const int xr = col & 7;

    for (int k0 = 0; k0 < K; k0 += 64) {
        __syncthreads();
#pragma unroll
        for (int r = 0; r < 4; r++)
            gload16(Ag + (size_t)(r * 32) * K + k0, AsW + r * 2048);
#pragma unroll
        for (int r = 0; r < 4; r++)
            gload16(Bg + (size_t)(r * 32) * K + k0, BsW + r * 2048);
        __syncthreads();

#pragma unroll
        for (int kk = 0; kk < 2; kk++) {
            const int cq = ((kk << 2) + quad) ^ xr;
            bf16x8 af[4], bfr[4];
#pragma unroll
            for (int mi = 0; mi < 4; mi++)
                af[mi] = *(const bf16x8*)(As + (wm + mi * 16 + col) * 64 + cq * 8);
#pragma unroll
            for (int ni = 0; ni < 4; ni++)
                bfr[ni] = *(const bf16x8*)(Bs + (wn + ni * 16 + col) * 64 + cq * 8);
#pragma unroll
            for (int mi = 0; mi < 4; mi++)
#pragma unroll
                for (int ni = 0; ni < 4; ni++)
                    acc[mi][ni] = __builtin_amdgcn_mfma_f32_16x16x32_bf16(
                        af[mi], bfr[ni], acc[mi][ni], 0, 0, 0);
        }
    }

    const int seg = n0 >> 10;
    const float* bias = sp.bias[seg];
    unsigned short* out = sp.out[seg];
    const int nb = (n0 & 1023) + wn;
    const bool trans = (seg == transSeg);

    float bv[4];
#pragma unroll
    for (int ni = 0; ni < 4; ni++) bv[ni] = bias[nb + ni * 16 + col];
#pragma unroll
    for (int mi = 0; mi < 4; mi++) {
#pragma unroll
        for (int r = 0; r < 4; r++) {
            int m = m0 + wm + mi * 16 + quad * 4 + r;
#pragma unroll
            for (int ni = 0; ni < 4; ni++) {
                int nl = nb + ni * 16 + col;
                float v = acc[mi][ni][r] + bv[ni];
                if (trans)
                    out[((size_t)(m >> 10) * 1024 + nl) * 1024 + (m & 1023)] = f2bu(v);
                else
                    out[(size_t)m * 1024 + nl] = f2bu(v);
            }
        }
    }
}

// ---------------------------------------------------------------------------
// Flash attention, MFMA 16x16x32 bf16.
//  LDS-staged K/V via global_load_lds with XOR-swizzled source (the verified
//  GEMM staging pattern). Linear Ks/Vs [64][64]; chunk c of row r stored at
//  position c^(r&7); fragment reads use c0=quad^(col&7), second half c0^4.
//  P transpose: per-wave padded LDS slab, barrier-free (verified round 5).
//  Fast v_exp_f32, diag-only causal mask, defer-max, reversed qt order.
// ---------------------------------------------------------------------------
template <bool CAUSAL>
__global__ __launch_bounds__(256) void fattn_k(
    const unsigned short* __restrict__ Q, const unsigned short* __restrict__ K,
    const unsigned short* __restrict__ Vt, unsigned short* __restrict__ O, int S)
{
    const int qt = CAUSAL ? ((int)gridDim.x - 1 - (int)blockIdx.x) : blockIdx.x;
    const int h = blockIdx.y, b = blockIdx.z;
    const int H64 = 1024;
    const int tid = threadIdx.x;
    const int w = tid >> 6, lane = tid & 63;
    const int quad = lane >> 4, col = lane & 15;

    __shared__ __align__(16) unsigned short Ks[64 * 64];
    __shared__ __align__(16) unsigned short Vs[64 * 64];
    __shared__ __align__(16) unsigned short Ps[4 * 16 * 72];

    const int qBase = qt * 64 + w * 16;
    const size_t qrow = ((size_t)b * S + qBase + col) * H64 + h * 64;

    // Q fragments pre-scaled by 0.125*log2(e): scores come out in log2 units.
    const float qscale = 0.125f * 1.44269504f;
    bf16x8 qf0, qf1;
    {
        bf16x8 r0 = *(const bf16x8*)(Q + qrow + quad * 8);
        bf16x8 r1 = *(const bf16x8*)(Q + qrow + quad * 8 + 32);
#pragma unroll
        for (int j = 0; j < 8; j++) {
            qf0[j] = (short)f2bu(bu2f((unsigned short)r0[j]) * qscale);
            qf1[j] = (short)f2bu(bu2f((unsigned short)r1[j]) * qscale);
        }
    }

    f32x4 o[4];
#pragma unroll
    for (int g = 0; g < 4; g++) o[g] = (f32x4){0.f, 0.f, 0.f, 0.f};
    float m_run[4], l_run[4];
#pragma unroll
    for (int r = 0; r < 4; r++) { m_run[r] = -1e30f; l_run[r] = 0.f; }

    // staging: wave w stages rows w*8+(lane>>3) (+32 for 2nd stripe);
    // source chunk xq = (lane&7)^(lane>>3); dest = linear base + lane*16B
    const int srow = (w << 3) + (lane >> 3);
    const int xq8 = ((lane & 7) ^ (lane >> 3)) * 8;
    const size_t kgbase = (size_t)b * S * H64 + h * 64;
    const size_t vgbase = ((size_t)b * 1024 + h * 64) * (size_t)S;
    const int xr = col & 7;
    const int c0 = quad ^ xr;

    const int nkt = CAUSAL ? (qt + 1) : (S >> 6);
    unsigned short* Pw = Ps + w * (16 * 72);

    for (int kt = 0; kt < nkt; kt++) {
        __syncthreads();
        {
            const unsigned short* kgp = K + kgbase + (size_t)(kt * 64 + srow) * H64 + xq8;
            gload16(kgp, Ks + w * 512);
            gload16(kgp + (size_t)32 * H64, Ks + 2048 + w * 512);
            const unsigned short* vgp = Vt + vgbase + (size_t)srow * S + kt * 64 + xq8;
            gload16(vgp, Vs + w * 512);
            gload16(vgp + (size_t)32 * S, Vs + 2048 + w * 512);
        }
        __syncthreads();

        // QK^T from swizzled LDS
        f32x4 s[4];
#pragma unroll
        for (int kg = 0; kg < 4; kg++) {
            const unsigned short* kr = Ks + (kg * 16 + col) * 64;
            bf16x8 k0 = *(const bf16x8*)(kr + c0 * 8);
            bf16x8 k1 = *(const bf16x8*)(kr + (c0 ^ 4) * 8);
            f32x4 a = (f32x4){0.f, 0.f, 0.f, 0.f};
            a = __builtin_amdgcn_mfma_f32_16x16x32_bf16(qf0, k0, a, 0, 0, 0);
            a = __builtin_amdgcn_mfma_f32_16x16x32_bf16(qf1, k1, a, 0, 0, 0);
            s[kg] = a;
        }

        // causal mask: only the diagonal tile needs it (wave-uniform branch)
        if (CAUSAL && kt == qt) {
#pragma unroll
            for (int kg = 0; kg < 4; kg++)
#pragma unroll
                for (int r = 0; r < 4; r++) {
                    int key = kg * 16 + col;
                    int q = w * 16 + quad * 4 + r;
                    if (key > q) s[kg][r] = -1e30f;
                }
        }

        float mx[4];
#pragma unroll
        for (int r = 0; r < 4; r++) {
            float m2 = fmaxf(fmaxf(s[0][r], s[1][r]), fmaxf(s[2][r], s[3][r]));
#pragma unroll
            for (int off = 1; off < 16; off <<= 1)
                m2 = fmaxf(m2, __shfl_xor(m2, off));
            mx[r] = m2;
        }

        // T13 defer-max: skip rescale when max growth <= 8 (P bounded by 2^8)
        bool defer = (mx[0] <= m_run[0] + 8.f) & (mx[1] <= m_run[1] + 8.f)
                   & (mx[2] <= m_run[2] + 8.f) & (mx[3] <= m_run[3] + 8.f);
        if (!__all(defer)) {
#pragma unroll
            for (int r = 0; r < 4; r++) {
                float mnew = fmaxf(m_run[r], mx[r]);
                float alpha = fexp2(m_run[r] - mnew);
                l_run[r] *= alpha;
#pragma unroll
                for (int g = 0; g < 4; g++) o[g][r] *= alpha;
                m_run[r] = mnew;
            }
        }

#pragma unroll
        for (int r = 0; r < 4; r++) {
            float ps = 0.f;
#pragma unroll
            for (int kg = 0; kg < 4; kg++) {
                float e = fexp2(s[kg][r] - m_run[r]);
                s[kg][r] = e;
                ps += e;
            }
#pragma unroll
            for (int off = 1; off < 16; off <<= 1)
                ps += __shfl_xor(ps, off);
            l_run[r] += ps;
        }

        // P transpose via per-wave LDS slab (no barrier: same-wave order)
#pragma unroll
        for (int kg = 0; kg < 4; kg++)
#pragma unroll
            for (int r = 0; r < 4; r++)
                Pw[(quad * 4 + r) * 72 + kg * 16 + col] = f2bu(s[kg][r]);

        bf16x8 p0 = *(const bf16x8*)(Pw + col * 72 + quad * 8);
        bf16x8 p1 = *(const bf16x8*)(Pw + col * 72 + quad * 8 + 32);

        // PV from swizzled LDS
#pragma unroll
        for (int g = 0; g < 4; g++) {
            const unsigned short* vr = Vs + (g * 16 + col) * 64;
            bf16x8 v0 = *(const bf16x8*)(vr + c0 * 8);
            bf16x8 v1 = *(const bf16x8*)(vr + (c0 ^ 4) * 8);
            o[g] = __builtin_amdgcn_mfma_f32_16x16x32_bf16(p0, v0, o[g], 0, 0, 0);
            o[g] = __builtin_amdgcn_mfma_f32_16x16x32_bf16(p1, v1, o[g], 0, 0, 0);
        }
    }

    const size_t orow = ((size_t)b * S + qBase) * H64 + h * 64;
#pragma unroll
    for (int r = 0; r < 4; r++) {
        float inv = 1.f / l_run[r];
        int q = quad * 4 + r;
#pragma unroll
        for (int g = 0; g < 4; g++)
            O[orow + (size_t)q * H64 + g * 16 + col] = f2bu(o[g][r] * inv);
    }
}

// ---------------------------------------------------------------------------
// LayerNorm (ddof=1, eps=1e-12)
// ---------------------------------------------------------------------------
template <typename TO>
__global__ __launch_bounds__(256) void ln_k(
    const float* __restrict__ X, const float* __restrict__ g,
    const float* __restrict__ bb, TO* __restrict__ O, int D)
{
    const int row = blockIdx.x;
    const int tid = threadIdx.x;
    __shared__ float xs[1024];
    __shared__ float red[256];
    const float* x = X + (size_t)row * D;

    float s = 0.f;
    for (int i = tid; i < D; i += 256) { float v = x[i]; xs[i] = v; s += v; }
    red[tid] = s;
    __syncthreads();
    for (int t = 128; t > 0; t >>= 1) {
        if (tid < t) red[tid] += red[tid + t];
        __syncthreads();
    }
    const float mean = red[0] / (float)D;
    __syncthreads();

    float s2 = 0.f;
    for (int i = tid; i < D; i += 256) { float d = xs[i] - mean; s2 += d * d; }
    red[tid] = s2;
    __syncthreads();
    for (int t = 128; t > 0; t >>= 1) {
        if (tid < t) red[tid] += red[tid + t];
        __syncthreads();
    }
    const float rstd = rsqrtf(red[0] / (float)(D - 1) + 1e-12f);

    TO* o = O + (size_t)row * D;
    for (int i = tid; i < D; i += 256)
        o[i] = fromF<TO>(g[i] * (xs[i] - mean) * rstd + bb[i]);
}

// ---------------------------------------------------------------------------
extern "C" void kernel_launch(void* const* d_in, const int* in_sizes, int n_in,
                              void* d_out, int out_size, void* d_ws, size_t ws_size,
                              hipStream_t stream)
{
    const int Bb = 4, S = 1024, D = 1024, F = 4096;
    const int M = Bb * S;
    const int H = 16;

    const float* dec = (const float*)d_in[0];
    const float* enc = (const float*)d_in[1];

    int base = 2;
    if (n_in >= 29 && in_sizes[2] == Bb * S * S) base = 3;

    const float* sa_wq = (const float*)d_in[base + 0];
    const float* sa_wk = (const float*)d_in[base + 1];
    const float* sa_wv = (const float*)d_in[base + 2];
    const float* sa_bq = (const float*)d_in[base + 3];
    const float* sa_bk = (const float*)d_in[base + 4];
    const float* sa_bv = (const float*)d_in[base + 5];
    const float* sa_wo = (const float*)d_in[base + 6];
    const float* sa_bo = (const float*)d_in[base + 7];
    const float* ca_wq = (const float*)d_in[base + 8];
    const float* ca_wk = (const float*)d_in[base + 9];
    const float* ca_wv = (const float*)d_in[base + 10];
    const float* ca_bq = (const float*)d_in[base + 11];
    const float* ca_bk = (const float*)d_in[base + 12];
    const float* ca_bv = (const float*)d_in[base + 13];
    const float* ca_wo = (const float*)d_in[base + 14];
    const float* ca_bo = (const float*)d_in[base + 15];
    const float* ff_w1 = (const float*)d_in[base + 16];
    const float* ff_b1 = (const float*)d_in[base + 17];
    const float* ff_w2 = (const float*)d_in[base + 18];
    const float* ff_b2 = (const float*)d_in[base + 19];
    const float* ln1_g = (const float*)d_in[base + 20];
    const float* ln1_b = (const float*)d_in[base + 21];
    const float* ln2_g = (const float*)d_in[base + 22];
    const float* ln2_b = (const float*)d_in[base + 23];
    const float* ln3_g = (const float*)d_in[base + 24];
    const float* ln3_b = (const float*)d_in[base + 25];

    // ws (64 MiB): SUM fp32 E | O1 bf16 E | O2 bf16 E | Q | K | Vt | AO (bf16 E each)
    //   HID bf16 4E overlays [Q..AO] (FFN phase); decB overlays AO (pre-attn phase).
    // d_out (16 MiB fp32) doubles as scratch until the final LN:
    //   Wt bf16 [0,8MiB) transposed weight (QKV fused: 6MiB); encB [8,16MiB).
    const size_t E = (size_t)M * D;
    float* SUM = (float*)d_ws;
    bf16* O1 = (bf16*)(SUM + E);
    bf16* O2 = O1 + E;
    bf16* Q  = O2 + E;
    bf16* Kb = Q + E;
    bf16* Vt = Kb + E;
    bf16* AO = Vt + E;
    bf16* HID = Q;
    unsigned short* decB = (unsigned short*)AO;           // dead once fattn writes AO
    unsigned short* Wt   = (unsigned short*)d_out;        // 8 MiB slot
    unsigned short* encB = (unsigned short*)d_out + 4 * 1024 * 1024;

    dim3 blk(256);
    dim3 gQKV(3 * D / 128, M / 128); // fused QKV: 24 x 32 = 768 blocks
    dim3 gKV(2 * D / 128, M / 128);  // fused KV:  16 x 32 = 512 blocks
    dim3 gN(D / 64, M / 128);        // narrow N=1024 gemms: 16 x 32 = 512 blocks
    dim3 gF(F / 128, M / 128);       // N=4096: 32 x 32
    dim3 gA(S / 64, H, Bb);
    dim3 gT3(D / 32, D / 32, 3);     // batched QKV transpose
    dim3 gT2z(D / 32, D / 32, 2);    // batched KV transpose
    dim3 gT(D / 32, D / 32, 1);      // single transpose K=N=1024
    dim3 gT1(D / 32, F / 32, 1);     // ff_w1: K=1024, N=4096
    dim3 gT2(F / 32, D / 32, 1);     // ff_w2: K=4096, N=1024

    // input converts
    cvt_k<<<M * D / 1024, blk, 0, stream>>>(dec, decB, M * D);
    cvt_k<<<M * D / 1024, blk, 0, stream>>>(enc, encB, M * D);

    // --- self-attention: fused QKV projection ---
    {
        WPtrs wp; wp.w[0] = sa_wq; wp.w[1] = sa_wk; wp.w[2] = sa_wv;
        wtrans_k<true><<<gT3, blk, 0, stream>>>(wp, Wt, D, D);
    }
    {
        SegArgs sp;
        sp.bias[0] = sa_bq; sp.bias[1] = sa_bk; sp.bias[2] = sa_bv;
        sp.out[0] = (unsigned short*)Q; sp.out[1] = (unsigned short*)Kb;
        sp.out[2] = (unsigned short*)Vt;
        gemm_seg<<<gQKV, blk, 0, stream>>>(decB, Wt, sp, M, D, 2);
    }
    fattn_k<true><<<gA, blk, 0, stream>>>((const unsigned short*)Q, (const unsigned short*)Kb,
                                          (const unsigned short*)Vt, (unsigned short*)AO, S);
    {
        WPtrs wp; wp.w[0] = sa_wo; wp.w[1] = nullptr; wp.w[2] = nullptr;
        wtrans_k<false><<<gT, blk, 0, stream>>>(wp, Wt, D, D);
    }
    gemm_mfma<float, float, false, true, 64><<<gN, blk, 0, stream>>>(
        (const unsigned short*)AO, Wt, sa_bo, dec, SUM, M, D, D);
    ln_k<bf16><<<M, blk, 0, stream>>>(SUM, ln1_g, ln1_b, O1, D);

    // --- cross-attention: Q separate (A=O1), fused KV (A=encB) ---
    {
        WPtrs wp; wp.w[0] = ca_wq; wp.w[1] = nullptr; wp.w[2] = nullptr;
        wtrans_k<true><<<gT, blk, 0, stream>>>(wp, Wt, D, D);
    }
    gemm_mfma<bf16, float, false, false, 64><<<gN, blk, 0, stream>>>(
        (const unsigned short*)O1, Wt, ca_bq, (const float*)nullptr, Q, M, D, D);
    {
        WPtrs wp; wp.w[0] = ca_wk; wp.w[1] = ca_wv; wp.w[2] = nullptr;
        wtrans_k<true><<<gT2z, blk, 0, stream>>>(wp, Wt, D, D);
    }
    {
        SegArgs sp;
        sp.bias[0] = ca_bk; sp.bias[1] = ca_bv; sp.bias[2] = nullptr;
        sp.out[0] = (unsigned short*)Kb; sp.out[1] = (unsigned short*)Vt;
        sp.out[2] = nullptr;
        gemm_seg<<<gKV, blk, 0, stream>>>(encB, Wt, sp, M, D, 1);
    }
    fattn_k<false><<<gA, blk, 0, stream>>>((const unsigned short*)Q, (const unsigned short*)Kb,
                                           (const unsigned short*)Vt, (unsigned short*)AO, S);
    {
        WPtrs wp; wp.w[0] = ca_wo; wp.w[1] = nullptr; wp.w[2] = nullptr;
        wtrans_k<false><<<gT, blk, 0, stream>>>(wp, Wt, D, D);
    }
    gemm_mfma<float, bf16, false, true, 64><<<gN, blk, 0, stream>>>(
        (const unsigned short*)AO, Wt, ca_bo, O1, SUM, M, D, D);
    ln_k<bf16><<<M, blk, 0, stream>>>(SUM, ln2_g, ln2_b, O2, D);

    // --- FFN ---
    {
        WPtrs wp; wp.w[0] = ff_w1; wp.w[1] = nullptr; wp.w[2] = nullptr;
        wtrans_k<false><<<gT1, blk, 0, stream>>>(wp, Wt, D, F);
    }
    gemm_mfma<bf16, float, true, false, 128><<<gF, blk, 0, stream>>>(
        (const unsigned short*)O2, Wt, ff_b1, (const float*)nullptr, HID, M, F, D);
    {
        WPtrs wp; wp.w[0] = ff_w2; wp.w[1] = nullptr; wp.w[2] = nullptr;
        wtrans_k<false><<<gT2, blk, 0, stream>>>(wp, Wt, F, D);
    }
    gemm_mfma<float, bf16, false, true, 64><<<gN, blk, 0, stream>>>(
        (const unsigned short*)HID, Wt, ff_b2, O2, SUM, M, D, F);
    ln_k<float><<<M, blk, 0, stream>>>(SUM, ln3_g, ln3_b, (float*)d_out, D);
}

// Round 8
// 539.863 us; speedup vs baseline: 1.2966x; 1.0735x over previous
//
#include <hip/hip_runtime.h>
#include <hip/hip_bf16.h>

using bf16 = __hip_bfloat16;
typedef __attribute__((ext_vector_type(8))) short bf16x8;
typedef __attribute__((ext_vector_type(4))) float f32x4;

__device__ __forceinline__ float toF(float x) { return x; }
__device__ __forceinline__ float toF(bf16 x) { return __bfloat162float(x); }

template <typename T> __device__ __forceinline__ T fromF(float x);
template <> __device__ __forceinline__ float fromF<float>(float x) { return x; }
template <> __device__ __forceinline__ bf16 fromF<bf16>(float x) { return __float2bfloat16(x); }

__device__ __forceinline__ unsigned short f2bu(float f) {
    bf16 h = __float2bfloat16(f);
    return *reinterpret_cast<unsigned short*>(&h);
}
__device__ __forceinline__ float bu2f(unsigned short u) {
    unsigned int x = ((unsigned int)u) << 16;
    return __uint_as_float(x);
}

// fast 2^x: raw v_exp_f32 (libm exp2f goes through slow OCML path)
__device__ __forceinline__ float fexp2(float x) {
#if __has_builtin(__builtin_amdgcn_exp2f)
    return __builtin_amdgcn_exp2f(x);
#else
    return __expf(x * 0.69314718f);
#endif
}

// async global->LDS, 16B per lane; LDS dest = wave-uniform base + lane*16
__device__ __forceinline__ void gload16(const unsigned short* g, unsigned short* l) {
    __builtin_amdgcn_global_load_lds(
        (const __attribute__((address_space(1))) unsigned int*)g,
        (__attribute__((address_space(3))) unsigned int*)l, 16, 0, 0);
}

// ---------------------------------------------------------------------------
// fp32 -> bf16 elementwise convert (vector 4/thread)
// ---------------------------------------------------------------------------
__global__ __launch_bounds__(256) void cvt_k(const float* __restrict__ X,
                                             unsigned short* __restrict__ Y, int n)
{
    int i = (blockIdx.x * 256 + threadIdx.x) * 4;
    if (i >= n) return;
    float4 v = *(const float4*)(X + i);
    ushort4 o;
    o.x = f2bu(v.x); o.y = f2bu(v.y); o.z = f2bu(v.z); o.w = f2bu(v.w);
    *(ushort4*)(Y + i) = o;
}

// ---------------------------------------------------------------------------
// Weight transpose: W fp32 (K,N) [or head-stacked (H,K,64), n=(h<<6)+dh]
//   -> Wt bf16 (N,K).  32x32 LDS tile, 256 threads.
//   blockIdx.z selects one of up to 3 source weights (batched QKV / KV).
// ---------------------------------------------------------------------------
struct WPtrs { const float* w[3]; };

template <bool HEADED>
__global__ __launch_bounds__(256) void wtrans_k(
    WPtrs wp, unsigned short* __restrict__ Wt, int K, int N)
{
    __shared__ float t[32][33];
    const float* __restrict__ W = wp.w[blockIdx.z];
    unsigned short* __restrict__ out = Wt + (size_t)blockIdx.z * K * N;
    const int k0 = blockIdx.x * 32, n0 = blockIdx.y * 32;
    const int tx = threadIdx.x & 31, ty = threadIdx.x >> 5;
#pragma unroll
    for (int i = 0; i < 4; i++) {
        int k = k0 + ty + 8 * i, n = n0 + tx;
        float v;
        if constexpr (HEADED) v = W[((size_t)(n >> 6) * K + k) * 64 + (n & 63)];
        else                  v = W[(size_t)k * N + n];
        t[ty + 8 * i][tx] = v;
    }
    __syncthreads();
#pragma unroll
    for (int i = 0; i < 4; i++)
        out[(size_t)(n0 + ty + 8 * i) * K + k0 + tx] = f2bu(t[tx][ty + 8 * i]);
}

// ---------------------------------------------------------------------------
// MFMA GEMM, global_load_lds staging + XOR-swizzled LDS (verified round 2).
//   C(M,N) = A(M,K)bf16 @ Bt(N,K)bf16^T + bias [+res] [ReLU]
// ---------------------------------------------------------------------------
template <typename TO, typename TR, bool RELU, bool HASRES, int BN>
__global__ __launch_bounds__(256) void gemm_mfma(
    const unsigned short* __restrict__ A, const unsigned short* __restrict__ Bt,
    const float* __restrict__ bias, const TR* __restrict__ res,
    TO* __restrict__ C, int M, int N, int K)
{
    constexpr int MI = (BN == 128) ? 4 : 2;
    __shared__ __align__(16) unsigned short As[128 * 64];
    __shared__ __align__(16) unsigned short Bs[BN * 64];

    const int tid = threadIdx.x;
    const int lane = tid & 63, wv = tid >> 6;
    const int quad = lane >> 4, col = lane & 15;
    const int m0 = blockIdx.y * 128, n0 = blockIdx.x * BN;
    const int wm = (BN == 128) ? (wv >> 1) * 64 : wv * 32;
    const int wn = (BN == 128) ? (wv & 1) * 64 : 0;

    f32x4 acc[MI][4];
#pragma unroll
    for (int i = 0; i < MI; i++)
#pragma unroll
        for (int j = 0; j < 4; j++) acc[i][j] = (f32x4){0.f, 0.f, 0.f, 0.f};

    const int rowl = (wv << 3) + (lane >> 3);
    const int xq = (lane & 7) ^ (lane >> 3);
    const unsigned short* Ag = A + (size_t)(m0 + rowl) * K + xq * 8;
    const unsigned short* Bg = Bt + (size_t)(n0 + rowl) * K + xq * 8;
    unsigned short* AsW = As + wv * 512;
    unsigned short* BsW = Bs + wv * 512;

    const int xr = col & 7;

    for (int k0 = 0; k0 < K; k0 += 64) {
        __syncthreads();
#pragma unroll
        for (int r = 0; r < 4; r++)
            gload16(Ag + (size_t)(r * 32) * K + k0, AsW + r * 2048);
#pragma unroll
        for (int r = 0; r < BN / 32; r++)
            gload16(Bg + (size_t)(r * 32) * K + k0, BsW + r * 2048);
        __syncthreads();

#pragma unroll
        for (int kk = 0; kk < 2; kk++) {
            const int cq = ((kk << 2) + quad) ^ xr;
            bf16x8 af[MI], bfr[4];
#pragma unroll
            for (int mi = 0; mi < MI; mi++)
                af[mi] = *(const bf16x8*)(As + (wm + mi * 16 + col) * 64 + cq * 8);
#pragma unroll
            for (int ni = 0; ni < 4; ni++)
                bfr[ni] = *(const bf16x8*)(Bs + (wn + ni * 16 + col) * 64 + cq * 8);
#pragma unroll
            for (int mi = 0; mi < MI; mi++)
#pragma unroll
                for (int ni = 0; ni < 4; ni++)
                    acc[mi][ni] = __builtin_amdgcn_mfma_f32_16x16x32_bf16(
                        af[mi], bfr[ni], acc[mi][ni], 0, 0, 0);
        }
    }

    float bv[4];
#pragma unroll
    for (int ni = 0; ni < 4; ni++) bv[ni] = bias[n0 + wn + ni * 16 + col];
#pragma unroll
    for (int mi = 0; mi < MI; mi++) {
#pragma unroll
        for (int r = 0; r < 4; r++) {
            int m = m0 + wm + mi * 16 + quad * 4 + r;
#pragma unroll
            for (int ni = 0; ni < 4; ni++) {
                int n = n0 + wn + ni * 16 + col;
                float v = acc[mi][ni][r] + bv[ni];
                if constexpr (HASRES) v += toF(res[(size_t)m * N + n]);
                if constexpr (RELU) v = v > 0.f ? v : 0.f;
                C[(size_t)m * N + n] = fromF<TO>(v);
            }
        }
    }
}

// ---------------------------------------------------------------------------
// Segmented MFMA GEMM (QKV / KV fused), same gload_lds+swizzle K-loop.
// ---------------------------------------------------------------------------
struct SegArgs {
    const float* bias[3];
    unsigned short* out[3];
};

__global__ __launch_bounds__(256) void gemm_seg(
    const unsigned short* __restrict__ A, const unsigned short* __restrict__ Bt,
    SegArgs sp, int M, int K, int transSeg)
{
    __shared__ __align__(16) unsigned short As[128 * 64];
    __shared__ __align__(16) unsigned short Bs[128 * 64];

    const int tid = threadIdx.x;
    const int lane = tid & 63, wv = tid >> 6;
    const int quad = lane >> 4, col = lane & 15;
    const int m0 = blockIdx.y * 128, n0 = blockIdx.x * 128;
    const int wm = (wv >> 1) * 64, wn = (wv & 1) * 64;

    f32x4 acc[4][4];
#pragma unroll
    for (int i = 0; i < 4; i++)
#pragma unroll
        for (int j = 0; j < 4; j++) acc[i][j] = (f32x4){0.f, 0.f, 0.f, 0.f};

    const int rowl = (wv << 3) + (lane >> 3);
    const int xq = (lane & 7) ^ (lane >> 3);
    const unsigned short* Ag = A + (size_t)(m0 + rowl) * K + xq * 8;
    const unsigned short* Bg = Bt + (size_t)(n0 + rowl) * K + xq * 8;
    unsigned short* AsW = As + wv * 512;
    unsigned short* BsW = Bs + wv * 512;
    const int xr = col & 7;

    for (int k0 = 0; k0 < K; k0 += 64) {
        __syncthreads();
#pragma unroll
        for (int r = 0; r < 4; r++)
            gload16(Ag + (size_t)(r * 32) * K + k0, AsW + r * 2048);
#pragma unroll
        for (int r = 0; r < 4; r++)
            gload16(Bg + (size_t)(r * 32) * K + k0, BsW + r * 2048);
        __syncthreads();

#pragma unroll
        for (int kk = 0; kk < 2; kk++) {
            const int cq = ((kk << 2) + quad) ^ xr;
            bf16x8 af[4], bfr[4];
#pragma unroll
            for (int mi = 0; mi < 4; mi++)
                af[mi] = *(const bf16x8*)(As + (wm + mi * 16 + col) * 64 + cq * 8);
#pragma unroll
            for (int ni = 0; ni < 4; ni++)
                bfr[ni] = *(const bf16x8*)(Bs + (wn + ni * 16 + col) * 64 + cq * 8);
#pragma unroll
            for (int mi = 0; mi < 4; mi++)
#pragma unroll
                for (int ni = 0; ni < 4; ni++)
                    acc[mi][ni] = __builtin_amdgcn_mfma_f32_16x16x32_bf16(
                        af[mi], bfr[ni], acc[mi][ni], 0, 0, 0);
        }
    }

    const int seg = n0 >> 10;
    const float* bias = sp.bias[seg];
    unsigned short* out = sp.out[seg];
    const int nb = (n0 & 1023) + wn;
    const bool trans = (seg == transSeg);

    float bv[4];
#pragma unroll
    for (int ni = 0; ni < 4; ni++) bv[ni] = bias[nb + ni * 16 + col];
#pragma unroll
    for (int mi = 0; mi < 4; mi++) {
#pragma unroll
        for (int r = 0; r < 4; r++) {
            int m = m0 + wm + mi * 16 + quad * 4 + r;
#pragma unroll
            for (int ni = 0; ni < 4; ni++) {
                int nl = nb + ni * 16 + col;
                float v = acc[mi][ni][r] + bv[ni];
                if (trans)
                    out[((size_t)(m >> 10) * 1024 + nl) * 1024 + (m & 1023)] = f2bu(v);
                else
                    out[(size_t)m * 1024 + nl] = f2bu(v);
            }
        }
    }
}

// ---------------------------------------------------------------------------
// Flash attention, MFMA 16x16x32 bf16 — round 8:
//  * swapped QK^T: s = mfma(kf, qf) -> lane holds 16 scores for ONE q (=col);
//    row max/sum = 15 local VALU + 2 shfl (was 4x4 shfl per phase).
//    m_run/l_run are per-lane scalars; o-layout values fetched via __shfl.
//  * 2-phase K prefetch: Ks double-buffered; V(t)+K(t+1) issued BEFORE
//    compute so the barrier's vmcnt(0) drain lands after ~1-2K cy of work.
//  * s_setprio(1) around MFMA clusters (T5).
//  LDS 33.25 KB -> 4 blocks/CU (grid-limited).
// ---------------------------------------------------------------------------
template <bool CAUSAL>
__global__ __launch_bounds__(256) void fattn_k(
    const unsigned short* __restrict__ Q, const unsigned short* __restrict__ K,
    const unsigned short* __restrict__ Vt, unsigned short* __restrict__ O, int S)
{
    const int qt = CAUSAL ? ((int)gridDim.x - 1 - (int)blockIdx.x) : blockIdx.x;
    const int h = blockIdx.y, b = blockIdx.z;
    const int H64 = 1024;
    const int tid = threadIdx.x;
    const int w = tid >> 6, lane = tid & 63;
    const int quad = lane >> 4, col = lane & 15;

    __shared__ __align__(16) unsigned short Ks[2][64 * 64];
    __shared__ __align__(16) unsigned short Vs[64 * 64];
    __shared__ __align__(16) unsigned short Ps[4 * 16 * 72];

    const int qBase = qt * 64 + w * 16;
    const size_t qrow = ((size_t)b * S + qBase + col) * H64 + h * 64;

    // Q fragments pre-scaled by 0.125*log2(e): scores come out in log2 units.
    const float qscale = 0.125f * 1.44269504f;
    bf16x8 qf0, qf1;
    {
        bf16x8 r0 = *(const bf16x8*)(Q + qrow + quad * 8);
        bf16x8 r1 = *(const bf16x8*)(Q + qrow + quad * 8 + 32);
#pragma unroll
        for (int j = 0; j < 8; j++) {
            qf0[j] = (short)f2bu(bu2f((unsigned short)r0[j]) * qscale);
            qf1[j] = (short)f2bu(bu2f((unsigned short)r1[j]) * qscale);
        }
    }

    f32x4 o[4];                       // o[g][r]: q = quad*4+r, d = g*16+col
#pragma unroll
    for (int g = 0; g < 4; g++) o[g] = (f32x4){0.f, 0.f, 0.f, 0.f};
    float m_run = -1e30f, l_run = 0.f;  // per-lane, q = qBase + col

    // staging: wave w stages rows w*8+(lane>>3) (+32 for 2nd stripe);
    // source chunk xq = (lane&7)^(lane>>3); dest = linear base + lane*16B
    const int srow = (w << 3) + (lane >> 3);
    const int xq8 = ((lane & 7) ^ (lane >> 3)) * 8;
    const size_t kgbase = (size_t)b * S * H64 + h * 64;
    const size_t vgbase = ((size_t)b * 1024 + h * 64) * (size_t)S;
    const int c0 = quad ^ (col & 7);

    const int nkt = CAUSAL ? (qt + 1) : (S >> 6);
    unsigned short* Pw = Ps + w * (16 * 72);

    // prologue: prefetch K(0) into buffer 0
    {
        const unsigned short* kgp = K + kgbase + (size_t)srow * H64 + xq8;
        gload16(kgp, &Ks[0][w * 512]);
        gload16(kgp + (size_t)32 * H64, &Ks[0][2048 + w * 512]);
    }
    __syncthreads();

    int cur = 0;
    for (int kt = 0; kt < nkt; kt++) {
        // issue V(kt) and K(kt+1) early — drained by the mid-tile barrier
        {
            const unsigned short* vgp = Vt + vgbase + (size_t)srow * S + kt * 64 + xq8;
            gload16(vgp, Vs + w * 512);
            gload16(vgp + (size_t)32 * S, Vs + 2048 + w * 512);
        }
        if (kt + 1 < nkt) {
            const unsigned short* kgp =
                K + kgbase + (size_t)((kt + 1) * 64 + srow) * H64 + xq8;
            gload16(kgp, &Ks[cur ^ 1][w * 512]);
            gload16(kgp + (size_t)32 * H64, &Ks[cur ^ 1][2048 + w * 512]);
        }

        // swapped QK^T: s[kg][r] = S^T -> key = kg*16+quad*4+r, q = col
        f32x4 s[4];
        __builtin_amdgcn_s_setprio(1);
#pragma unroll
        for (int kg = 0; kg < 4; kg++) {
            const unsigned short* kr = &Ks[cur][(kg * 16 + col) * 64];
            bf16x8 k0 = *(const bf16x8*)(kr + c0 * 8);
            bf16x8 k1 = *(const bf16x8*)(kr + (c0 ^ 4) * 8);
            f32x4 a = (f32x4){0.f, 0.f, 0.f, 0.f};
            a = __builtin_amdgcn_mfma_f32_16x16x32_bf16(k0, qf0, a, 0, 0, 0);
            a = __builtin_amdgcn_mfma_f32_16x16x32_bf16(k1, qf1, a, 0, 0, 0);
            s[kg] = a;
        }
        __builtin_amdgcn_s_setprio(0);

        // causal mask: only the diagonal tile (wave-uniform branch)
        if (CAUSAL && kt == qt) {
            const int ql = w * 16 + col;
#pragma unroll
            for (int kg = 0; kg < 4; kg++)
#pragma unroll
                for (int r = 0; r < 4; r++)
                    if (kg * 16 + quad * 4 + r > ql) s[kg][r] = -1e30f;
        }

        // per-lane row max (15 local + 2 shfl)
        float mx = s[0][0];
#pragma unroll
        for (int kg = 0; kg < 4; kg++)
#pragma unroll
            for (int r = 0; r < 4; r++) mx = fmaxf(mx, s[kg][r]);
        mx = fmaxf(mx, __shfl_xor(mx, 16));
        mx = fmaxf(mx, __shfl_xor(mx, 32));

        // T13 defer-max: skip rescale when max growth <= 8
        if (!__all(mx <= m_run + 8.f)) {
            float mnew = fmaxf(m_run, mx);
            float alpha = fexp2(m_run - mnew);   // for q = col
            l_run *= alpha;
            m_run = mnew;
#pragma unroll
            for (int r = 0; r < 4; r++) {
                float ar = __shfl(alpha, (lane & 48) | (quad * 4 + r));
#pragma unroll
                for (int g = 0; g < 4; g++) o[g][r] *= ar;
            }
        }

        // exp + per-lane sum (15 local + 2 shfl)
        float ps = 0.f;
#pragma unroll
        for (int kg = 0; kg < 4; kg++)
#pragma unroll
            for (int r = 0; r < 4; r++) {
                float e = fexp2(s[kg][r] - m_run);
                s[kg][r] = e;
                ps += e;
            }
        ps += __shfl_xor(ps, 16);
        ps += __shfl_xor(ps, 32);
        l_run += ps;

        // P store: Pw[q=col][key], 4 consecutive keys packed per uint2
#pragma unroll
        for (int kg = 0; kg < 4; kg++) {
            uint2 pk;
            pk.x = (unsigned)f2bu(s[kg][0]) | ((unsigned)f2bu(s[kg][1]) << 16);
            pk.y = (unsigned)f2bu(s[kg][2]) | ((unsigned)f2bu(s[kg][3]) << 16);
            *(uint2*)(Pw + col * 72 + kg * 16 + quad * 4) = pk;
        }

        __syncthreads();   // V(kt) ready (vmcnt drain); K(kt+1) mostly landed

        bf16x8 p0 = *(const bf16x8*)(Pw + col * 72 + quad * 8);
        bf16x8 p1 = *(const bf16x8*)(Pw + col * 72 + quad * 8 + 32);

        __builtin_amdgcn_s_setprio(1);
#pragma unroll
        for (int g = 0; g < 4; g++) {
            const unsigned short* vr = Vs + (g * 16 + col) * 64;
            bf16x8 v0 = *(const bf16x8*)(vr + c0 * 8);
            bf16x8 v1 = *(const bf16x8*)(vr + (c0 ^ 4) * 8);
            o[g] = __builtin_amdgcn_mfma_f32_16x16x32_bf16(p0, v0, o[g], 0, 0, 0);
            o[g] = __builtin_amdgcn_mfma_f32_16x16x32_bf16(p1, v1, o[g], 0, 0, 0);
        }
        __builtin_amdgcn_s_setprio(0);

        __syncthreads();   // WAR: all waves done with Vs/Ks[cur] before restage
        cur ^= 1;
    }

    const size_t orow = ((size_t)b * S + qBase) * H64 + h * 64;
#pragma unroll
    for (int r = 0; r < 4; r++) {
        float lr = __shfl(l_run, (lane & 48) | (quad * 4 + r));
        float inv = 1.f / lr;
        int q = quad * 4 + r;
#pragma unroll
        for (int g = 0; g < 4; g++)
            O[orow + (size_t)q * H64 + g * 16 + col] = f2bu(o[g][r] * inv);
    }
}

// ---------------------------------------------------------------------------
// LayerNorm (ddof=1, eps=1e-12)
// ---------------------------------------------------------------------------
template <typename TO>
__global__ __launch_bounds__(256) void ln_k(
    const float* __restrict__ X, const float* __restrict__ g,
    const float* __restrict__ bb, TO* __restrict__ O, int D)
{
    const int row = blockIdx.x;
    const int tid = threadIdx.x;
    __shared__ float xs[1024];
    __shared__ float red[256];
    const float* x = X + (size_t)row * D;

    float s = 0.f;
    for (int i = tid; i < D; i += 256) { float v = x[i]; xs[i] = v; s += v; }
    red[tid] = s;
    __syncthreads();
    for (int t = 128; t > 0; t >>= 1) {
        if (tid < t) red[tid] += red[tid + t];
        __syncthreads();
    }
    const float mean = red[0] / (float)D;
    __syncthreads();

    float s2 = 0.f;
    for (int i = tid; i < D; i += 256) { float d = xs[i] - mean; s2 += d * d; }
    red[tid] = s2;
    __syncthreads();
    for (int t = 128; t > 0; t >>= 1) {
        if (tid < t) red[tid] += red[tid + t];
        __syncthreads();
    }
    const float rstd = rsqrtf(red[0] / (float)(D - 1) + 1e-12f);

    TO* o = O + (size_t)row * D;
    for (int i = tid; i < D; i += 256)
        o[i] = fromF<TO>(g[i] * (xs[i] - mean) * rstd + bb[i]);
}

// ---------------------------------------------------------------------------
extern "C" void kernel_launch(void* const* d_in, const int* in_sizes, int n_in,
                              void* d_out, int out_size, void* d_ws, size_t ws_size,
                              hipStream_t stream)
{
    const int Bb = 4, S = 1024, D = 1024, F = 4096;
    const int M = Bb * S;
    const int H = 16;

    const float* dec = (const float*)d_in[0];
    const float* enc = (const float*)d_in[1];

    int base = 2;
    if (n_in >= 29 && in_sizes[2] == Bb * S * S) base = 3;

    const float* sa_wq = (const float*)d_in[base + 0];
    const float* sa_wk = (const float*)d_in[base + 1];
    const float* sa_wv = (const float*)d_in[base + 2];
    const float* sa_bq = (const float*)d_in[base + 3];
    const float* sa_bk = (const float*)d_in[base + 4];
    const float* sa_bv = (const float*)d_in[base + 5];
    const float* sa_wo = (const float*)d_in[base + 6];
    const float* sa_bo = (const float*)d_in[base + 7];
    const float* ca_wq = (const float*)d_in[base + 8];
    const float* ca_wk = (const float*)d_in[base + 9];
    const float* ca_wv = (const float*)d_in[base + 10];
    const float* ca_bq = (const float*)d_in[base + 11];
    const float* ca_bk = (const float*)d_in[base + 12];
    const float* ca_bv = (const float*)d_in[base + 13];
    const float* ca_wo = (const float*)d_in[base + 14];
    const float* ca_bo = (const float*)d_in[base + 15];
    const float* ff_w1 = (const float*)d_in[base + 16];
    const float* ff_b1 = (const float*)d_in[base + 17];
    const float* ff_w2 = (const float*)d_in[base + 18];
    const float* ff_b2 = (const float*)d_in[base + 19];
    const float* ln1_g = (const float*)d_in[base + 20];
    const float* ln1_b = (const float*)d_in[base + 21];
    const float* ln2_g = (const float*)d_in[base + 22];
    const float* ln2_b = (const float*)d_in[base + 23];
    const float* ln3_g = (const float*)d_in[base + 24];
    const float* ln3_b = (const float*)d_in[base + 25];

    // ws (64 MiB): SUM fp32 E | O1 bf16 E | O2 bf16 E | Q | K | Vt | AO (bf16 E each)
    //   HID bf16 4E overlays [Q..AO] (FFN phase); decB overlays AO (pre-attn phase).
    // d_out (16 MiB fp32) doubles as scratch until the final LN:
    //   Wt bf16 [0,8MiB) transposed weight (QKV fused: 6MiB); encB [8,16MiB).
    const size_t E = (size_t)M * D;
    float* SUM = (float*)d_ws;
    bf16* O1 = (bf16*)(SUM + E);
    bf16* O2 = O1 + E;
    bf16* Q  = O2 + E;
    bf16* Kb = Q + E;
    bf16* Vt = Kb + E;
    bf16* AO = Vt + E;
    bf16* HID = Q;
    unsigned short* decB = (unsigned short*)AO;           // dead once fattn writes AO
    unsigned short* Wt   = (unsigned short*)d_out;        // 8 MiB slot
    unsigned short* encB = (unsigned short*)d_out + 4 * 1024 * 1024;

    dim3 blk(256);
    dim3 gQKV(3 * D / 128, M / 128); // fused QKV: 24 x 32 = 768 blocks
    dim3 gKV(2 * D / 128, M / 128);  // fused KV:  16 x 32 = 512 blocks
    dim3 gN(D / 64, M / 128);        // narrow N=1024 gemms: 16 x 32 = 512 blocks
    dim3 gF(F / 128, M / 128);       // N=4096: 32 x 32
    dim3 gA(S / 64, H, Bb);
    dim3 gT3(D / 32, D / 32, 3);     // batched QKV transpose
    dim3 gT2z(D / 32, D / 32, 2);    // batched KV transpose
    dim3 gT(D / 32, D / 32, 1);      // single transpose K=N=1024
    dim3 gT1(D / 32, F / 32, 1);     // ff_w1: K=1024, N=4096
    dim3 gT2(F / 32, D / 32, 1);     // ff_w2: K=4096, N=1024

    // input converts
    cvt_k<<<M * D / 1024, blk, 0, stream>>>(dec, decB, M * D);
    cvt_k<<<M * D / 1024, blk, 0, stream>>>(enc, encB, M * D);

    // --- self-attention: fused QKV projection ---
    {
        WPtrs wp; wp.w[0] = sa_wq; wp.w[1] = sa_wk; wp.w[2] = sa_wv;
        wtrans_k<true><<<gT3, blk, 0, stream>>>(wp, Wt, D, D);
    }
    {
        SegArgs sp;
        sp.bias[0] = sa_bq; sp.bias[1] = sa_bk; sp.bias[2] = sa_bv;
        sp.out[0] = (unsigned short*)Q; sp.out[1] = (unsigned short*)Kb;
        sp.out[2] = (unsigned short*)Vt;
        gemm_seg<<<gQKV, blk, 0, stream>>>(decB, Wt, sp, M, D, 2);
    }
    fattn_k<true><<<gA, blk, 0, stream>>>((const unsigned short*)Q, (const unsigned short*)Kb,
                                          (const unsigned short*)Vt, (unsigned short*)AO, S);
    {
        WPtrs wp; wp.w[0] = sa_wo; wp.w[1] = nullptr; wp.w[2] = nullptr;
        wtrans_k<false><<<gT, blk, 0, stream>>>(wp, Wt, D, D);
    }
    gemm_mfma<float, float, false, true, 64><<<gN, blk, 0, stream>>>(
        (const unsigned short*)AO, Wt, sa_bo, dec, SUM, M, D, D);
    ln_k<bf16><<<M, blk, 0, stream>>>(SUM, ln1_g, ln1_b, O1, D);

    // --- cross-attention: Q separate (A=O1), fused KV (A=encB) ---
    {
        WPtrs wp; wp.w[0] = ca_wq; wp.w[1] = nullptr; wp.w[2] = nullptr;
        wtrans_k<true><<<gT, blk, 0, stream>>>(wp, Wt, D, D);
    }
    gemm_mfma<bf16, float, false, false, 64><<<gN, blk, 0, stream>>>(
        (const unsigned short*)O1, Wt, ca_bq, (const float*)nullptr, Q, M, D, D);
    {
        WPtrs wp; wp.w[0] = ca_wk; wp.w[1] = ca_wv; wp.w[2] = nullptr;
        wtrans_k<true><<<gT2z, blk, 0, stream>>>(wp, Wt, D, D);
    }
    {
        SegArgs sp;
        sp.bias[0] = ca_bk; sp.bias[1] = ca_bv; sp.bias[2] = nullptr;
        sp.out[0] = (unsigned short*)Kb; sp.out[1] = (unsigned short*)Vt;
        sp.out[2] = nullptr;
        gemm_seg<<<gKV, blk, 0, stream>>>(encB, Wt, sp, M, D, 1);
    }
    fattn_k<false><<<gA, blk, 0, stream>>>((const unsigned short*)Q, (const unsigned short*)Kb,
                                           (const unsigned short*)Vt, (unsigned short*)AO, S);
    {
        WPtrs wp; wp.w[0] = ca_wo; wp.w[1] = nullptr; wp.w[2] = nullptr;
        wtrans_k<false><<<gT, blk, 0, stream>>>(wp, Wt, D, D);
    }
    gemm_mfma<float, bf16, false, true, 64><<<gN, blk, 0, stream>>>(
        (const unsigned short*)AO, Wt, ca_bo, O1, SUM, M, D, D);
    ln_k<bf16><<<M, blk, 0, stream>>>(SUM, ln2_g, ln2_b, O2, D);

    // --- FFN ---
    {
        WPtrs wp; wp.w[0] = ff_w1; wp.w[1] = nullptr; wp.w[2] = nullptr;
        wtrans_k<false><<<gT1, blk, 0, stream>>>(wp, Wt, D, F);
    }
    gemm_mfma<bf16, float, true, false, 128><<<gF, blk, 0, stream>>>(
        (const unsigned short*)O2, Wt, ff_b1, (const float*)nullptr, HID, M, F, D);
    {
        WPtrs wp; wp.w[0] = ff_w2; wp.w[1] = nullptr; wp.w[2] = nullptr;
        wtrans_k<false><<<gT2, blk, 0, stream>>>(wp, Wt, F, D);
    }
    gemm_mfma<float, bf16, false, true, 64><<<gN, blk, 0, stream>>>(
        (const unsigned short*)HID, Wt, ff_b2, O2, SUM, M, D, F);
    ln_k<float><<<M, blk, 0, stream>>>(SUM, ln3_g, ln3_b, (float*)d_out, D);
}